// Round 3
// baseline (610.663 us; speedup 1.0000x reference)
//
#include <hip/hip_runtime.h>
#include <hip/hip_cooperative_groups.h>
#include <cfloat>
#include <cmath>

#define N_Q 4096
#define N_S 1600
#define DIM 1024
#define N_C 64
#define KNN 12
#define MAX_ITER 50
#define EPS_CONV 1e-4f
#define NBLK 256         // tail_loop grid size
#define ADJ_CAP 96       // per-row LDS adjacency capacity (multiple of 8)
#define CHK 256          // P0a: Pt features staged per LDS chunk

typedef _Float16 h8 __attribute__((ext_vector_type(8)));
typedef float    f4 __attribute__((ext_vector_type(4)));

__device__ __forceinline__ float wave_max64(float v){
  #pragma unroll
  for (int o = 32; o; o >>= 1) v = fmaxf(v, __shfl_xor(v, o, 64));
  return v;
}
__device__ __forceinline__ float wave_sum64(float v){
  #pragma unroll
  for (int o = 32; o; o >>= 1) v += __shfl_xor(v, o, 64);
  return v;
}
__device__ __forceinline__ float wave_min64(float v){
  #pragma unroll
  for (int o = 32; o; o >>= 1) v = fminf(v, __shfl_xor(v, o, 64));
  return v;
}

// coherent (device-visible) element accesses for cross-block-communicated data
__device__ __forceinline__ float aload(const float* p){
  return __hip_atomic_load(p, __ATOMIC_RELAXED, __HIP_MEMORY_SCOPE_AGENT);
}
__device__ __forceinline__ void astore(float* p, float v){
  __hip_atomic_store(p, v, __ATOMIC_RELAXED, __HIP_MEMORY_SCOPE_AGENT);
}
__device__ __forceinline__ int aloadi(const int* p){
  return __hip_atomic_load(p, __ATOMIC_RELAXED, __HIP_MEMORY_SCOPE_AGENT);
}
__device__ __forceinline__ void astorei(int* p, int v){
  __hip_atomic_store(p, v, __ATOMIC_RELAXED, __HIP_MEMORY_SCOPE_AGENT);
}
__device__ __forceinline__ unsigned long long aload64(const unsigned long long* p){
  return __hip_atomic_load(p, __ATOMIC_RELAXED, __HIP_MEMORY_SCOPE_AGENT);
}
__device__ __forceinline__ void astore64(unsigned long long* p, unsigned long long v){
  __hip_atomic_store(p, v, __ATOMIC_RELAXED, __HIP_MEMORY_SCOPE_AGENT);
}

// ---- prototypes (unchanged): parallel ordered compaction.
__global__ __launch_bounds__(256) void proto_kernel(
    const float* __restrict__ fs, const int* __restrict__ ys,
    float* __restrict__ Pt, float* __restrict__ pn)
{
  const int c = blockIdx.x, t = threadIdx.x;
  __shared__ int list[N_S];
  __shared__ int pref[256];
  __shared__ int lcount;

  int loc[7]; int cnt = 0;
  const int base = t * 7;                  // 256*7 = 1792 >= 1600
  #pragma unroll
  for (int u = 0; u < 7; u++){
    const int i = base + u;
    if (i < N_S && ys[i] == c) loc[cnt++] = i;
  }
  pref[t] = cnt;
  __syncthreads();
  for (int off = 1; off < 256; off <<= 1){
    int v = (t >= off) ? pref[t - off] : 0;
    __syncthreads();
    pref[t] += v;
    __syncthreads();
  }
  const int start = pref[t] - cnt;
  for (int u = 0; u < cnt; u++) list[start + u] = loc[u];
  if (t == 255) lcount = pref[255];
  __syncthreads();

  const int n = lcount;
  float a0 = 0.f, a1 = 0.f, a2 = 0.f, a3 = 0.f;
  for (int m = 0; m < n; m++){
    const float* r = fs + (size_t)list[m] * DIM;
    a0 += r[t]; a1 += r[t + 256]; a2 += r[t + 512]; a3 += r[t + 768];
  }
  const float inv = 1.0f / fmaxf((float)n, 1.0f);
  const float v0 = a0*inv, v1 = a1*inv, v2 = a2*inv, v3 = a3*inv;
  Pt[(t      )*N_C + c] = v0;
  Pt[(t + 256)*N_C + c] = v1;
  Pt[(t + 512)*N_C + c] = v2;
  Pt[(t + 768)*N_C + c] = v3;
  __shared__ float red[256];
  red[t] = v0*v0 + v1*v1 + v2*v2 + v3*v3;
  __syncthreads();
  for (int o = 128; o; o >>= 1){ if (t < o) red[t] += red[t + o]; __syncthreads(); }
  if (t == 0) pn[c] = red[0];
}

// ---- fused per-row sqnorm + fp32 -> (f16 hi, f16 lo) split (unchanged).
__global__ __launch_bounds__(256) void prep_kernel(
    const float* __restrict__ X, float* __restrict__ qn,
    _Float16* __restrict__ Xh, _Float16* __restrict__ Xl)
{
  const int i = blockIdx.x, t = threadIdx.x;
  const float* r = X + (size_t)i * DIM;
  const float v0 = r[t], v1 = r[t+256], v2 = r[t+512], v3 = r[t+768];
  const size_t b = (size_t)i * DIM;
  _Float16 h0 = (_Float16)v0, h1 = (_Float16)v1, h2 = (_Float16)v2, h3 = (_Float16)v3;
  Xh[b + t      ] = h0; Xl[b + t      ] = (_Float16)(v0 - (float)h0);
  Xh[b + t + 256] = h1; Xl[b + t + 256] = (_Float16)(v1 - (float)h1);
  Xh[b + t + 512] = h2; Xl[b + t + 512] = (_Float16)(v2 - (float)h2);
  Xh[b + t + 768] = h3; Xl[b + t + 768] = (_Float16)(v3 - (float)h3);
  __shared__ float red[256];
  red[t] = v0*v0 + v1*v1 + v2*v2 + v3*v3;
  __syncthreads();
  for (int o = 128; o; o >>= 1){ if (t < o) red[t] += red[t + o]; __syncthreads(); }
  if (t == 0) qn[i] = red[0];
}

// ---- pairwise distances via f16 split-precision MFMA.
//      R16: XCD-chunked block swizzle (1024 blocks, %8==0 -> bijective).
//      Each XCD owns a 4-wide column slab of the 32x32 block grid -> its
//      B-panels (Xh/Xl cols, ~2MB) stay L2-resident instead of being
//      re-fetched 32x from LLC. Pure index remap: per-output FP order
//      unchanged -> Dq bit-identical.
__global__ __launch_bounds__(256, 3) void dist_mfma(
    const _Float16* __restrict__ Xh, const _Float16* __restrict__ Xl,
    const float* __restrict__ qn, float* __restrict__ Dq)
{
  const int t = threadIdx.x, w = t >> 6, l = t & 63;
  const int lb  = blockIdx.y * 32 + blockIdx.x;   // dispatch-linear id
  const int xcd = lb & 7, k = lb >> 3;            // round-robin XCD map
  const int bxs = xcd * 4 + (k >> 5);             // 4 col-blocks per XCD
  const int bys = k & 31;
  const int i0 = bys * 128 + (w >> 1) * 64;
  const int j0 = bxs * 128 + (w & 1) * 64;
  const int fr = l & 15;
  const int kq = (l >> 4) * 8;

  f4 acc[4][4];
  #pragma unroll
  for (int a = 0; a < 4; a++)
    #pragma unroll
    for (int b = 0; b < 4; b++) acc[a][b] = (f4){0.f, 0.f, 0.f, 0.f};

  const _Float16* pAh = Xh + (size_t)(i0 + fr) * DIM + kq;
  const _Float16* pAl = Xl + (size_t)(i0 + fr) * DIM + kq;
  const _Float16* pBh = Xh + (size_t)(j0 + fr) * DIM + kq;
  const _Float16* pBl = Xl + (size_t)(j0 + fr) * DIM + kq;

  #pragma unroll 1
  for (int k0 = 0; k0 < DIM; k0 += 32){
    h8 ah[4], al[4];
    #pragma unroll
    for (int sm = 0; sm < 4; sm++){
      const size_t o = (size_t)(sm * 16) * DIM + k0;
      ah[sm] = *(const h8*)(pAh + o);
      al[sm] = *(const h8*)(pAl + o);
    }
    #pragma unroll
    for (int sn = 0; sn < 4; sn++){
      const size_t o = (size_t)(sn * 16) * DIM + k0;
      h8 bh = *(const h8*)(pBh + o);
      h8 bl = *(const h8*)(pBl + o);
      #pragma unroll
      for (int sm = 0; sm < 4; sm++){
        acc[sm][sn] = __builtin_amdgcn_mfma_f32_16x16x32_f16(ah[sm], bh, acc[sm][sn], 0, 0, 0);
        acc[sm][sn] = __builtin_amdgcn_mfma_f32_16x16x32_f16(ah[sm], bl, acc[sm][sn], 0, 0, 0);
        acc[sm][sn] = __builtin_amdgcn_mfma_f32_16x16x32_f16(al[sm], bh, acc[sm][sn], 0, 0, 0);
      }
    }
  }

  const int cr = (l >> 4) * 4;
  const int cc = l & 15;
  #pragma unroll
  for (int sm = 0; sm < 4; sm++){
    #pragma unroll
    for (int r = 0; r < 4; r++){
      const int row = i0 + sm * 16 + cr + r;
      const float qi = qn[row];
      float* dstrow = &Dq[(size_t)row * N_Q];
      #pragma unroll
      for (int sn = 0; sn < 4; sn++){
        const int col = j0 + sn * 16 + cc;
        float d2 = qi + qn[col] - 2.0f * acc[sm][sn][r];
        dstrow[col] = sqrtf(fmaxf(d2, 0.f));
      }
    }
  }
}

// ---- per-row 13 smallest (ties -> smaller index), row in registers (unchanged).
__global__ __launch_bounds__(256) void topk_kernel(
    const float* __restrict__ Dq, int* __restrict__ nbr,
    float* __restrict__ dnbr, float* __restrict__ sigma)
{
  const int i = blockIdx.x, t = threadIdx.x;
  const float* row = Dq + (size_t)i * N_Q;
  float r[16];
  #pragma unroll
  for (int u = 0; u < 16; u++) r[u] = row[t + u * 256];

  __shared__ float pvf[4];
  __shared__ int   pif[4];
  __shared__ int   bwi_s;

  for (int s = 0; s < KNN + 1; s++){
    float best = FLT_MAX; int bj = 0x7fffffff;
    #pragma unroll
    for (int u = 0; u < 16; u++){
      float v = r[u];
      if (v < best){ best = v; bj = t + u * 256; }
    }
    #pragma unroll
    for (int o = 32; o; o >>= 1){
      float ov = __shfl_xor(best, o, 64); int oj = __shfl_xor(bj, o, 64);
      if (ov < best || (ov == best && oj < bj)){ best = ov; bj = oj; }
    }
    if ((t & 63) == 0){ pvf[t >> 6] = best; pif[t >> 6] = bj; }
    __syncthreads();
    if (t == 0){
      float bv = pvf[0]; int bi2 = pif[0];
      #pragma unroll
      for (int w2 = 1; w2 < 4; w2++){
        float v2 = pvf[w2]; int i2 = pif[w2];
        if (v2 < bv || (v2 == bv && i2 < bi2)){ bv = v2; bi2 = i2; }
      }
      bwi_s = bi2;
      if (s >= 1){ nbr[i*KNN + s - 1] = bi2; dnbr[i*KNN + s - 1] = bv; }
      if (s == KNN) sigma[i] = bv + 1e-8f;
    }
    __syncthreads();
    const int widx = bwi_s;
    if ((widx & 255) == t) r[widx >> 8] = FLT_MAX;
  }
}

// ============ hierarchical monotonic grid barrier (setup phases only) ============
__device__ __forceinline__ void gbar_leader(int* garr, int* gcnt, int* gen, int target){
  const int g = blockIdx.x >> 4;
  int old = __hip_atomic_fetch_add(&garr[g * 32], 1, __ATOMIC_RELAXED, __HIP_MEMORY_SCOPE_AGENT);
  if ((old & 15) == 15){
    int o2 = __hip_atomic_fetch_add(gcnt, 1, __ATOMIC_RELAXED, __HIP_MEMORY_SCOPE_AGENT);
    if ((o2 & 15) == 15)
      __hip_atomic_fetch_add(gen, 1, __ATOMIC_RELAXED, __HIP_MEMORY_SCOPE_AGENT);
  }
  while (__hip_atomic_load(gen, __ATOMIC_RELAXED, __HIP_MEMORY_SCOPE_AGENT) < target)
    __builtin_amdgcn_s_sleep(1);
}

// ============ packed {phase, delta} flag barrier — contiguous 8B slots ============
__device__ __forceinline__ void pbar_wave0(
    unsigned long long* pslot, int ph, int* sdm, float* sdelta_sh, int lane)
{
  const int par = ph & 1;
  unsigned long long* base = pslot + (size_t)par * NBLK;
  if (lane == 0){
    int myd = sdm[par]; sdm[par] = 0;
    unsigned long long pack =
        ((unsigned long long)(unsigned int)myd << 32) | (unsigned int)ph;
    __builtin_amdgcn_s_waitcnt(0);          // all prior y stores drained
    astore64(&base[blockIdx.x], pack);
  }
  int mx;
  while (1){
    unsigned long long v0 = aload64(&base[lane      ]);
    unsigned long long v1 = aload64(&base[lane +  64]);
    unsigned long long v2 = aload64(&base[lane + 128]);
    unsigned long long v3 = aload64(&base[lane + 192]);
    int f0 = (int)(unsigned int)v0, f1 = (int)(unsigned int)v1;
    int f2 = (int)(unsigned int)v2, f3 = (int)(unsigned int)v3;
    int mn = f0 < f1 ? f0 : f1;
    mn = f2 < mn ? f2 : mn;
    mn = f3 < mn ? f3 : mn;
    if (__all(mn >= ph)){
      int d0 = (int)(v0 >> 32), d1 = (int)(v1 >> 32);
      int d2 = (int)(v2 >> 32), d3 = (int)(v3 >> 32);
      mx = d0 > d1 ? d0 : d1;
      mx = d2 > mx ? d2 : mx;
      mx = d3 > mx ? d3 : mx;
      break;
    }
    __builtin_amdgcn_s_sleep(1);
  }
  #pragma unroll
  for (int o = 32; o; o >>= 1){ int ox = __shfl_xor(mx, o, 64); mx = ox > mx ? ox : mx; }
  if (lane == 0) *sdelta_sh = __int_as_float(mx);
}

// ---- SpMV over one row from LDS adjacency.
//      R16: y-gather uses PLAIN CACHED loads (was agent-scope/L2-bypassing).
//      Within an iteration src is read-only (double-buffered), so L2/L1
//      caching is safe; freshness across iterations is guaranteed by the
//      per-iteration acquire fence (buffer_inv) in the loop below. Per-XCD
//      the 3.2MB of gathers draw from a 1MB y-buffer -> ~3.2x L2 reuse,
//      cutting LLC traffic ~3x. Values read are bit-identical.
__device__ __forceinline__ float spmv_row(
    const float* __restrict__ src, const int2* adj,
    const int* __restrict__ colA, const float* __restrict__ wA,
    int p0, int p1v, int lane)
{
  const int deg  = p1v - p0;
  const int ncap = deg < ADJ_CAP ? deg : ADJ_CAP;
  const int nfull = ncap & ~7;
  float s0=0.f,s1=0.f,s2=0.f,s3=0.f,s4=0.f,s5=0.f,s6=0.f,s7=0.f;
  int q = 0;
  #pragma unroll 1
  for (; q < nfull; q += 8){
    int2 a0 = adj[q  ], a1 = adj[q+1], a2 = adj[q+2], a3 = adj[q+3];
    int2 a4 = adj[q+4], a5 = adj[q+5], a6 = adj[q+6], a7 = adj[q+7];
    s0 = fmaf(__int_as_float(a0.y), src[a0.x + lane], s0);
    s1 = fmaf(__int_as_float(a1.y), src[a1.x + lane], s1);
    s2 = fmaf(__int_as_float(a2.y), src[a2.x + lane], s2);
    s3 = fmaf(__int_as_float(a3.y), src[a3.x + lane], s3);
    s4 = fmaf(__int_as_float(a4.y), src[a4.x + lane], s4);
    s5 = fmaf(__int_as_float(a5.y), src[a5.x + lane], s5);
    s6 = fmaf(__int_as_float(a6.y), src[a6.x + lane], s6);
    s7 = fmaf(__int_as_float(a7.y), src[a7.x + lane], s7);
  }
  if (deg > ADJ_CAP){
    int qg = p0 + ADJ_CAP;
    for (; qg + 8 <= p1v; qg += 8){
      s0 = fmaf(wA[qg    ], src[colA[qg    ] + lane], s0);
      s1 = fmaf(wA[qg + 1], src[colA[qg + 1] + lane], s1);
      s2 = fmaf(wA[qg + 2], src[colA[qg + 2] + lane], s2);
      s3 = fmaf(wA[qg + 3], src[colA[qg + 3] + lane], s3);
      s4 = fmaf(wA[qg + 4], src[colA[qg + 4] + lane], s4);
      s5 = fmaf(wA[qg + 5], src[colA[qg + 5] + lane], s5);
      s6 = fmaf(wA[qg + 6], src[colA[qg + 6] + lane], s6);
      s7 = fmaf(wA[qg + 7], src[colA[qg + 7] + lane], s7);
    }
    for (; qg < p1v; qg++)
      s0 = fmaf(wA[qg], src[colA[qg] + lane], s0);
  } else {
    #pragma unroll 1
    for (; q < deg; q++){
      int2 a = adj[q];
      s0 = fmaf(__int_as_float(a.y), src[a.x + lane], s0);
    }
  }
  return ((s0+s1)+(s2+s3)) + ((s4+s5)+(s6+s7));
}

// ---- fused tail. R16: y-gather via L2-cached plain loads + per-iteration
//      wave0 acquire fence (buffer_inv) after barrier-detect. Release side
//      unchanged: each wave drains its own y stores (sc1, to LLC) at
//      __syncthreads before wave0 publishes the flag.
__global__ __launch_bounds__(1024, 4) void tail_loop(
    const float* __restrict__ Xq, const float* __restrict__ Pt,
    const float* __restrict__ pn, const float* __restrict__ qn,
    const int* __restrict__ nbr, const float* __restrict__ dnbr,
    const float* __restrict__ sigma,
    float* d2min, float* denom, float* wh,
    float* rowsum, int* indeg, int* rowptr, int* fillc,
    int* colA, float* wA, float* buf0, float* buf1,
    unsigned long long* pslot,
    int* gcnt, int* gen, int* garr, int* __restrict__ out)
{
  __shared__ int   sdm[2];
  __shared__ float sdelta;
  __shared__ union {
    float pchunk[CHK * N_C];                // 64 KB, P0a staging
    struct {
      int   ipart[1024];
      int   hist[1024];
      float cand[4096];
      int   candn, b1s, b2s;
    } s;
  } U;
  __shared__ int2  adjL[16 * ADJ_CAP];      // 12 KB, per-wave adjacency

  const int tid  = threadIdx.x;
  const int lane = tid & 63;
  const int wv   = tid >> 6;
  const int row  = blockIdx.x * 16 + wv;
  if (tid == 0){ sdm[0] = 0; sdm[1] = 0; }

  // ---------- P0a: a-row via LDS-staged Pt chunks (bit-exact dp order) ----------
  const float* xr = Xq + (size_t)row * DIM;
  const f4*    xr4 = (const f4*)xr;
  float dp[8];
  #pragma unroll
  for (int u = 0; u < 8; u++) dp[u] = 0.f;

  for (int f0 = 0; f0 < DIM; f0 += CHK){
    // cooperative stage: CHK*64 floats = 4096 f4; 1024 threads x 4 f4
    const f4* srcv = (const f4*)(Pt + (size_t)f0 * N_C);
    f4* dstv = (f4*)U.pchunk;
    #pragma unroll
    for (int u = 0; u < 4; u++) dstv[tid + u * 1024] = srcv[tid + u * 1024];
    __syncthreads();
    #pragma unroll 1
    for (int f = 0; f < CHK; f += 8){
      const f4 xa = xr4[(f0 + f) >> 2];
      const f4 xb = xr4[((f0 + f) >> 2) + 1];
      const float* pc = U.pchunk + f * N_C + lane;
      dp[0] = fmaf(xa[0], pc[0      ], dp[0]);
      dp[1] = fmaf(xa[1], pc[N_C    ], dp[1]);
      dp[2] = fmaf(xa[2], pc[N_C * 2], dp[2]);
      dp[3] = fmaf(xa[3], pc[N_C * 3], dp[3]);
      dp[4] = fmaf(xb[0], pc[N_C * 4], dp[4]);
      dp[5] = fmaf(xb[1], pc[N_C * 5], dp[5]);
      dp[6] = fmaf(xb[2], pc[N_C * 6], dp[6]);
      dp[7] = fmaf(xb[3], pc[N_C * 7], dp[7]);
    }
    __syncthreads();                        // before next chunk overwrite
  }
  const float dot = ((dp[0]+dp[1])+(dp[2]+dp[3])) + ((dp[4]+dp[5])+(dp[6]+dp[7]));
  const float av  = fmaxf(qn[row] + pn[lane] - 2.0f * dot, 0.0f);
  const float d2m = wave_min64(av);
  if (lane == 0) astore(&d2min[row], d2m);

  // ---------- P0b: edge weights + degrees ----------
  const int e = blockIdx.x * 1024 + tid;
  if (e < N_Q * KNN){
    const int i = e / KNN;
    const int j = nbr[e];
    float wgt = 0.5f * expf(-dnbr[e] / (sigma[i] * sigma[j]));
    astore(&wh[e], wgt);
    atomicAdd(&rowsum[i], wgt);
    atomicAdd(&rowsum[j], wgt);
    atomicAdd(&indeg[j], 1);
  }

  __syncthreads();
  if (tid == 0) gbar_leader(garr, gcnt, gen, 1);
  __syncthreads();

  // ---------- P1: y0 + scan (block 0) + median (block 1) ----------
  float xv = -av;
  float m = wave_max64(xv), ee = expf(xv - m), ss = wave_sum64(ee);
  float prev = ee / ss;                    // y0
  astore(&buf0[row * N_C + lane], prev);

  if (blockIdx.x == 0){
    int* ipart = U.s.ipart;
    const int base = tid * 4;
    int c0 = aloadi(&indeg[base]),     c1 = aloadi(&indeg[base + 1]);
    int c2 = aloadi(&indeg[base + 2]), c3 = aloadi(&indeg[base + 3]);
    const int s4 = c0 + c1 + c2 + c3;
    ipart[tid] = s4;
    __syncthreads();
    for (int off = 1; off < 1024; off <<= 1){
      int v = (tid >= off) ? ipart[tid - off] : 0;
      __syncthreads();
      ipart[tid] += v;
      __syncthreads();
    }
    int run = ipart[tid] - s4;
    astorei(&rowptr[base    ], KNN * (base    ) + run); run += c0;
    astorei(&rowptr[base + 1], KNN * (base + 1) + run); run += c1;
    astorei(&rowptr[base + 2], KNN * (base + 2) + run); run += c2;
    astorei(&rowptr[base + 3], KNN * (base + 3) + run);
    if (tid == 1023) astorei(&rowptr[N_Q], KNN * N_Q + ipart[1023]);
  }
  if (blockIdx.x == 1){
    int*   hist = U.s.hist;
    float* cand = U.s.cand;
    const int base = tid * 4;
    float dv[4];
    #pragma unroll
    for (int u = 0; u < 4; u++) dv[u] = sqrtf(aload(&d2min[base + u]));
    float mn = fminf(fminf(dv[0], dv[1]), fminf(dv[2], dv[3]));
    float mx = fmaxf(fmaxf(dv[0], dv[1]), fmaxf(dv[2], dv[3]));
    mn = wave_min64(mn); mx = wave_max64(mx);
    if (lane == 0){ cand[wv] = mn; cand[wv + 16] = mx; }
    __syncthreads();
    if (tid == 0){
      float a = cand[0], b = cand[16];
      for (int k = 1; k < 16; k++){ a = fminf(a, cand[k]); b = fmaxf(b, cand[16 + k]); }
      cand[32] = a; cand[33] = b;
    }
    __syncthreads();
    mn = cand[32]; mx = cand[33];
    const float rng = mx - mn;
    const float scale = (rng > 0.f) ? (1024.0f / rng) : 0.f;
    hist[tid] = 0;
    __syncthreads();
    int bidx[4];
    #pragma unroll
    for (int u = 0; u < 4; u++){
      int b = (int)((dv[u] - mn) * scale);
      b = b < 0 ? 0 : (b > 1023 ? 1023 : b);
      bidx[u] = b;
      atomicAdd(&hist[b], 1);
    }
    __syncthreads();
    for (int off = 1; off < 1024; off <<= 1){
      int v = (tid >= off) ? hist[tid - off] : 0;
      __syncthreads();
      hist[tid] += v;
      __syncthreads();
    }
    if (hist[tid] >= 2048 && (tid == 0 || hist[tid - 1] < 2048)) U.s.b1s = tid;
    if (hist[tid] >= 2049 && (tid == 0 || hist[tid - 1] < 2049)) U.s.b2s = tid;
    if (tid == 0) U.s.candn = 0;
    __syncthreads();
    const int b1 = U.s.b1s, b2 = U.s.b2s;
    const int cntBefore = (b1 > 0) ? hist[b1 - 1] : 0;
    #pragma unroll
    for (int u = 0; u < 4; u++){
      if (bidx[u] >= b1 && bidx[u] <= b2){
        int pos = atomicAdd(&U.s.candn, 1);
        cand[pos] = dv[u];
      }
    }
    __syncthreads();
    const int mcnt = U.s.candn;
    int P = 2; while (P < mcnt) P <<= 1;
    for (int i2 = mcnt + tid; i2 < P; i2 += 1024) cand[i2] = FLT_MAX;
    __syncthreads();
    for (int k = 2; k <= P; k <<= 1){
      for (int st = k >> 1; st > 0; st >>= 1){
        for (int i2 = tid; i2 < P; i2 += 1024){
          int j2 = i2 ^ st;
          if (j2 > i2){
            float a2 = cand[i2], b3 = cand[j2];
            bool up = ((i2 & k) == 0);
            if (up ? (a2 > b3) : (a2 < b3)){ cand[i2] = b3; cand[j2] = a2; }
          }
        }
        __syncthreads();
      }
    }
    if (tid == 0){
      float v1 = cand[2047 - cntBefore], v2 = cand[2048 - cntBefore];
      float med = 0.5f * (v1 + v2);
      astore(denom, 2.0f * med * med + 1e-8f);
    }
  }

  __syncthreads();
  if (tid == 0) gbar_leader(garr, gcnt, gen, 2);
  __syncthreads();

  // ---------- P2: CSR fill + per-row coef ----------
  if (e < N_Q * KNN){
    const int i = e / KNN, tt = e % KNN;
    const int j = nbr[e];
    const float wgt = aload(&wh[e]);
    const int p = aloadi(&rowptr[i]) + tt;
    colA[p] = j * N_C; wA[p] = wgt;
    const int q = aloadi(&rowptr[j]) + KNN + atomicAdd(&fillc[j], 1);
    colA[q] = i * N_C; wA[q] = wgt;
  }
  const float cf = expf(-d2m / aload(denom)) / (aload(&rowsum[row]) + 1e-8f);
  const int p0  = aloadi(&rowptr[row]);
  const int p1v = aloadi(&rowptr[row + 1]);

  __builtin_amdgcn_fence(__ATOMIC_RELEASE, "agent");
  __syncthreads();
  if (tid == 0) gbar_leader(garr, gcnt, gen, 3);
  __syncthreads();
  __builtin_amdgcn_fence(__ATOMIC_ACQUIRE, "agent");

  // ---------- preload loop-invariant adjacency into LDS ----------
  {
    const int deg  = p1v - p0;
    const int ncap = deg < ADJ_CAP ? deg : ADJ_CAP;
    for (int u = lane; u < ncap; u += 64)
      adjL[wv * ADJ_CAP + u] = make_int2(colA[p0 + u], __float_as_int(wA[p0 + u]));
  }
  __syncthreads();
  const int2* adj = adjL + wv * ADJ_CAP;

  // ---------- P3: y1 = step(y0); publish delta via pbar phase 1 ----------
  // buf0 gather is covered by the acquire fence above (post phase-3 gbar).
  float cur;
  {
    float sum = spmv_row(buf0, adj, colA, wA, p0, p1v, lane);
    float xv2 = -av + cf * sum;
    float mm = wave_max64(xv2), e2 = expf(xv2 - mm), ss2 = wave_sum64(e2);
    cur = e2 / ss2;
    astore(&buf1[row * N_C + lane], cur);
  }
  float dm = wave_max64(fabsf(cur - prev));
  if (lane == 0) atomicMax(&sdm[1], __float_as_int(dm));
  __syncthreads();                         // each wave drains its y stores
  if (wv == 0){
    pbar_wave0(pslot, 1, sdm, &sdelta, lane);
    // invalidate stale L1/L2 y-lines before next gather (all block's waves
    // are on this CU; barrier below orders their loads after this inv)
    __builtin_amdgcn_fence(__ATOMIC_ACQUIRE, "agent");
  }
  __syncthreads();
  float delta = sdelta;

  // ---------- P4: the while-loop ----------
  int par = 1;                             // buffer currently holding y_new
  for (int t = 0;; t++){
    if (t >= MAX_ITER || delta < EPS_CONV) break;
    const float* src = par ? buf1 : buf0;
    float*       dst = par ? buf0 : buf1;
    float sum = spmv_row(src, adj, colA, wA, p0, p1v, lane);
    float xv2 = -av + cf * sum;
    float mm = wave_max64(xv2), e2 = expf(xv2 - mm), ss2 = wave_sum64(e2);
    float nxt = e2 / ss2;
    astore(&dst[row * N_C + lane], nxt);
    const int ph = t + 2;
    dm = wave_max64(fabsf(nxt - cur));
    if (lane == 0) atomicMax(&sdm[ph & 1], __float_as_int(dm));
    __syncthreads();
    if (wv == 0){
      pbar_wave0(pslot, ph, sdm, &sdelta, lane);
      __builtin_amdgcn_fence(__ATOMIC_ACQUIRE, "agent");
    }
    __syncthreads();
    delta = sdelta;
    prev = cur; cur = nxt; par ^= 1;
  }

  // argmax of y (prev); first occurrence on ties
  float bv = prev; int bi = lane;
  #pragma unroll
  for (int o = 32; o; o >>= 1){
    float ov = __shfl_xor(bv, o, 64); int oi = __shfl_xor(bi, o, 64);
    if (ov > bv || (ov == bv && oi < bi)){ bv = ov; bi = oi; }
  }
  if (lane == 0) out[row] = bi;
}

extern "C" void kernel_launch(void* const* d_in, const int* in_sizes, int n_in,
                              void* d_out, int out_size, void* d_ws, size_t ws_size,
                              hipStream_t stream)
{
  const float* feat_s = (const float*)d_in[0];
  const int*   y_s    = (const int*)d_in[1];
  const float* feat_q = (const float*)d_in[2];
  int* out = (int*)d_out;

  char* wp = (char*)d_ws;
  auto alloc = [&](size_t bytes) -> char* {
    char* p = wp;
    wp += (bytes + 255) & ~(size_t)255;
    return p;
  };
  float*     Dq  = (float*)alloc((size_t)N_Q * N_Q * 4);     // 64 MB
  _Float16*  Xh  = (_Float16*)alloc((size_t)N_Q * DIM * 2);  // 8 MB
  _Float16*  Xl  = (_Float16*)alloc((size_t)N_Q * DIM * 2);  // 8 MB
  float* Pt     = (float*)alloc((size_t)DIM * N_C * 4);
  float* pn     = (float*)alloc(N_C * 4);
  float* qn     = (float*)alloc(N_Q * 4);
  float* d2min  = (float*)alloc(N_Q * 4);
  float* denom  = (float*)alloc(256);
  int*   nbr    = (int*)alloc((size_t)N_Q * KNN * 4);
  float* dnbr   = (float*)alloc((size_t)N_Q * KNN * 4);
  float* sigma  = (float*)alloc(N_Q * 4);
  float* wh     = (float*)alloc((size_t)N_Q * KNN * 4);
  int*   rowptr = (int*)alloc((N_Q + 1) * 4);
  int*   colA   = (int*)alloc((size_t)2 * N_Q * KNN * 4);
  float* wA     = (float*)alloc((size_t)2 * N_Q * KNN * 4);
  float* buf0   = (float*)alloc((size_t)N_Q * N_C * 4);
  float* buf1   = (float*)alloc((size_t)N_Q * N_C * 4);
  // zero-region: rowsum | indeg | fillc | syncw | garr | pslot (packed, 4KB)
  const size_t zbytes = (size_t)N_Q*12 + 256 + 2048 + 2 * NBLK * 8;
  char*  zbase  = alloc(zbytes);
  float* rowsum = (float*)(zbase);
  int*   indeg  = (int*)(zbase + N_Q*4);
  int*   fillc  = (int*)(zbase + N_Q*8);
  int*   syncw  = (int*)(zbase + N_Q*12);
  int*   garr   = (int*)(zbase + N_Q*12 + 256);
  unsigned long long* pslot = (unsigned long long*)(zbase + N_Q*12 + 256 + 2048);

  hipMemsetAsync(zbase, 0, zbytes, stream);

  proto_kernel <<<N_C, 256, 0, stream>>>(feat_s, y_s, Pt, pn);
  prep_kernel  <<<N_Q, 256, 0, stream>>>(feat_q, qn, Xh, Xl);
  dist_mfma    <<<dim3(N_Q/128, N_Q/128), 256, 0, stream>>>(Xh, Xl, qn, Dq);
  topk_kernel  <<<N_Q, 256, 0, stream>>>(Dq, nbr, dnbr, sigma);

  int* gcnt = &syncw[0];
  int* gen  = &syncw[32];
  const float* Xq = feat_q;
  void* args[] = {&Xq, &Pt, &pn, &qn, &nbr, &dnbr, &sigma,
                  &d2min, &denom, &wh, &rowsum, &indeg, &rowptr, &fillc,
                  &colA, &wA, &buf0, &buf1, &pslot,
                  &gcnt, &gen, &garr, &out};
  hipLaunchCooperativeKernel((void*)tail_loop, dim3(NBLK), dim3(1024), args, 0, stream);
}

// Round 4
// 603.004 us; speedup vs baseline: 1.0127x; 1.0127x over previous
//
#include <hip/hip_runtime.h>
#include <hip/hip_cooperative_groups.h>
#include <cfloat>
#include <cmath>

#define N_Q 4096
#define N_S 1600
#define DIM 1024
#define N_C 64
#define KNN 12
#define MAX_ITER 50
#define EPS_CONV 1e-4f
#define NBLK 256         // tail_loop grid size
#define ADJ_CAP 96       // per-row LDS adjacency capacity (multiple of 8)
#define CHK 256          // P0a: Pt features staged per LDS chunk

typedef _Float16 h8 __attribute__((ext_vector_type(8)));
typedef float    f4 __attribute__((ext_vector_type(4)));

__device__ __forceinline__ float wave_max64(float v){
  #pragma unroll
  for (int o = 32; o; o >>= 1) v = fmaxf(v, __shfl_xor(v, o, 64));
  return v;
}
__device__ __forceinline__ float wave_sum64(float v){
  #pragma unroll
  for (int o = 32; o; o >>= 1) v += __shfl_xor(v, o, 64);
  return v;
}
__device__ __forceinline__ float wave_min64(float v){
  #pragma unroll
  for (int o = 32; o; o >>= 1) v = fminf(v, __shfl_xor(v, o, 64));
  return v;
}

// coherent (device-visible) element accesses for cross-block-communicated data
__device__ __forceinline__ float aload(const float* p){
  return __hip_atomic_load(p, __ATOMIC_RELAXED, __HIP_MEMORY_SCOPE_AGENT);
}
__device__ __forceinline__ void astore(float* p, float v){
  __hip_atomic_store(p, v, __ATOMIC_RELAXED, __HIP_MEMORY_SCOPE_AGENT);
}
__device__ __forceinline__ int aloadi(const int* p){
  return __hip_atomic_load(p, __ATOMIC_RELAXED, __HIP_MEMORY_SCOPE_AGENT);
}
__device__ __forceinline__ void astorei(int* p, int v){
  __hip_atomic_store(p, v, __ATOMIC_RELAXED, __HIP_MEMORY_SCOPE_AGENT);
}
__device__ __forceinline__ unsigned long long aload64(const unsigned long long* p){
  return __hip_atomic_load(p, __ATOMIC_RELAXED, __HIP_MEMORY_SCOPE_AGENT);
}
__device__ __forceinline__ void astore64(unsigned long long* p, unsigned long long v){
  __hip_atomic_store(p, v, __ATOMIC_RELAXED, __HIP_MEMORY_SCOPE_AGENT);
}

// ---- prototypes (unchanged): parallel ordered compaction.
__global__ __launch_bounds__(256) void proto_kernel(
    const float* __restrict__ fs, const int* __restrict__ ys,
    float* __restrict__ Pt, float* __restrict__ pn)
{
  const int c = blockIdx.x, t = threadIdx.x;
  __shared__ int list[N_S];
  __shared__ int pref[256];
  __shared__ int lcount;

  int loc[7]; int cnt = 0;
  const int base = t * 7;                  // 256*7 = 1792 >= 1600
  #pragma unroll
  for (int u = 0; u < 7; u++){
    const int i = base + u;
    if (i < N_S && ys[i] == c) loc[cnt++] = i;
  }
  pref[t] = cnt;
  __syncthreads();
  for (int off = 1; off < 256; off <<= 1){
    int v = (t >= off) ? pref[t - off] : 0;
    __syncthreads();
    pref[t] += v;
    __syncthreads();
  }
  const int start = pref[t] - cnt;
  for (int u = 0; u < cnt; u++) list[start + u] = loc[u];
  if (t == 255) lcount = pref[255];
  __syncthreads();

  const int n = lcount;
  float a0 = 0.f, a1 = 0.f, a2 = 0.f, a3 = 0.f;
  for (int m = 0; m < n; m++){
    const float* r = fs + (size_t)list[m] * DIM;
    a0 += r[t]; a1 += r[t + 256]; a2 += r[t + 512]; a3 += r[t + 768];
  }
  const float inv = 1.0f / fmaxf((float)n, 1.0f);
  const float v0 = a0*inv, v1 = a1*inv, v2 = a2*inv, v3 = a3*inv;
  Pt[(t      )*N_C + c] = v0;
  Pt[(t + 256)*N_C + c] = v1;
  Pt[(t + 512)*N_C + c] = v2;
  Pt[(t + 768)*N_C + c] = v3;
  __shared__ float red[256];
  red[t] = v0*v0 + v1*v1 + v2*v2 + v3*v3;
  __syncthreads();
  for (int o = 128; o; o >>= 1){ if (t < o) red[t] += red[t + o]; __syncthreads(); }
  if (t == 0) pn[c] = red[0];
}

// ---- fused per-row sqnorm + fp32 -> (f16 hi, f16 lo) split (unchanged).
__global__ __launch_bounds__(256) void prep_kernel(
    const float* __restrict__ X, float* __restrict__ qn,
    _Float16* __restrict__ Xh, _Float16* __restrict__ Xl)
{
  const int i = blockIdx.x, t = threadIdx.x;
  const float* r = X + (size_t)i * DIM;
  const float v0 = r[t], v1 = r[t+256], v2 = r[t+512], v3 = r[t+768];
  const size_t b = (size_t)i * DIM;
  _Float16 h0 = (_Float16)v0, h1 = (_Float16)v1, h2 = (_Float16)v2, h3 = (_Float16)v3;
  Xh[b + t      ] = h0; Xl[b + t      ] = (_Float16)(v0 - (float)h0);
  Xh[b + t + 256] = h1; Xl[b + t + 256] = (_Float16)(v1 - (float)h1);
  Xh[b + t + 512] = h2; Xl[b + t + 512] = (_Float16)(v2 - (float)h2);
  Xh[b + t + 768] = h3; Xl[b + t + 768] = (_Float16)(v3 - (float)h3);
  __shared__ float red[256];
  red[t] = v0*v0 + v1*v1 + v2*v2 + v3*v3;
  __syncthreads();
  for (int o = 128; o; o >>= 1){ if (t < o) red[t] += red[t + o]; __syncthreads(); }
  if (t == 0) qn[i] = red[0];
}

// ---- pairwise distances via f16 split-precision MFMA.
//      XCD-chunked block swizzle (kept from R16: bit-identical, ~neutral-to-
//      slightly-positive on L2 locality).
__global__ __launch_bounds__(256, 3) void dist_mfma(
    const _Float16* __restrict__ Xh, const _Float16* __restrict__ Xl,
    const float* __restrict__ qn, float* __restrict__ Dq)
{
  const int t = threadIdx.x, w = t >> 6, l = t & 63;
  const int lb  = blockIdx.y * 32 + blockIdx.x;   // dispatch-linear id
  const int xcd = lb & 7, k = lb >> 3;            // round-robin XCD map
  const int bxs = xcd * 4 + (k >> 5);             // 4 col-blocks per XCD
  const int bys = k & 31;
  const int i0 = bys * 128 + (w >> 1) * 64;
  const int j0 = bxs * 128 + (w & 1) * 64;
  const int fr = l & 15;
  const int kq = (l >> 4) * 8;

  f4 acc[4][4];
  #pragma unroll
  for (int a = 0; a < 4; a++)
    #pragma unroll
    for (int b = 0; b < 4; b++) acc[a][b] = (f4){0.f, 0.f, 0.f, 0.f};

  const _Float16* pAh = Xh + (size_t)(i0 + fr) * DIM + kq;
  const _Float16* pAl = Xl + (size_t)(i0 + fr) * DIM + kq;
  const _Float16* pBh = Xh + (size_t)(j0 + fr) * DIM + kq;
  const _Float16* pBl = Xl + (size_t)(j0 + fr) * DIM + kq;

  #pragma unroll 1
  for (int k0 = 0; k0 < DIM; k0 += 32){
    h8 ah[4], al[4];
    #pragma unroll
    for (int sm = 0; sm < 4; sm++){
      const size_t o = (size_t)(sm * 16) * DIM + k0;
      ah[sm] = *(const h8*)(pAh + o);
      al[sm] = *(const h8*)(pAl + o);
    }
    #pragma unroll
    for (int sn = 0; sn < 4; sn++){
      const size_t o = (size_t)(sn * 16) * DIM + k0;
      h8 bh = *(const h8*)(pBh + o);
      h8 bl = *(const h8*)(pBl + o);
      #pragma unroll
      for (int sm = 0; sm < 4; sm++){
        acc[sm][sn] = __builtin_amdgcn_mfma_f32_16x16x32_f16(ah[sm], bh, acc[sm][sn], 0, 0, 0);
        acc[sm][sn] = __builtin_amdgcn_mfma_f32_16x16x32_f16(ah[sm], bl, acc[sm][sn], 0, 0, 0);
        acc[sm][sn] = __builtin_amdgcn_mfma_f32_16x16x32_f16(al[sm], bh, acc[sm][sn], 0, 0, 0);
      }
    }
  }

  const int cr = (l >> 4) * 4;
  const int cc = l & 15;
  #pragma unroll
  for (int sm = 0; sm < 4; sm++){
    #pragma unroll
    for (int r = 0; r < 4; r++){
      const int row = i0 + sm * 16 + cr + r;
      const float qi = qn[row];
      float* dstrow = &Dq[(size_t)row * N_Q];
      #pragma unroll
      for (int sn = 0; sn < 4; sn++){
        const int col = j0 + sn * 16 + cc;
        float d2 = qi + qn[col] - 2.0f * acc[sm][sn][r];
        dstrow[col] = sqrtf(fmaxf(d2, 0.f));
      }
    }
  }
}

// ---- per-row 13 smallest (ties -> smaller index), row in registers (unchanged).
__global__ __launch_bounds__(256) void topk_kernel(
    const float* __restrict__ Dq, int* __restrict__ nbr,
    float* __restrict__ dnbr, float* __restrict__ sigma)
{
  const int i = blockIdx.x, t = threadIdx.x;
  const float* row = Dq + (size_t)i * N_Q;
  float r[16];
  #pragma unroll
  for (int u = 0; u < 16; u++) r[u] = row[t + u * 256];

  __shared__ float pvf[4];
  __shared__ int   pif[4];
  __shared__ int   bwi_s;

  for (int s = 0; s < KNN + 1; s++){
    float best = FLT_MAX; int bj = 0x7fffffff;
    #pragma unroll
    for (int u = 0; u < 16; u++){
      float v = r[u];
      if (v < best){ best = v; bj = t + u * 256; }
    }
    #pragma unroll
    for (int o = 32; o; o >>= 1){
      float ov = __shfl_xor(best, o, 64); int oj = __shfl_xor(bj, o, 64);
      if (ov < best || (ov == best && oj < bj)){ best = ov; bj = oj; }
    }
    if ((t & 63) == 0){ pvf[t >> 6] = best; pif[t >> 6] = bj; }
    __syncthreads();
    if (t == 0){
      float bv = pvf[0]; int bi2 = pif[0];
      #pragma unroll
      for (int w2 = 1; w2 < 4; w2++){
        float v2 = pvf[w2]; int i2 = pif[w2];
        if (v2 < bv || (v2 == bv && i2 < bi2)){ bv = v2; bi2 = i2; }
      }
      bwi_s = bi2;
      if (s >= 1){ nbr[i*KNN + s - 1] = bi2; dnbr[i*KNN + s - 1] = bv; }
      if (s == KNN) sigma[i] = bv + 1e-8f;
    }
    __syncthreads();
    const int widx = bwi_s;
    if ((widx & 255) == t) r[widx >> 8] = FLT_MAX;
  }
}

// ============ hierarchical monotonic grid barrier (setup phases only) ============
__device__ __forceinline__ void gbar_leader(int* garr, int* gcnt, int* gen, int target){
  const int g = blockIdx.x >> 4;
  int old = __hip_atomic_fetch_add(&garr[g * 32], 1, __ATOMIC_RELAXED, __HIP_MEMORY_SCOPE_AGENT);
  if ((old & 15) == 15){
    int o2 = __hip_atomic_fetch_add(gcnt, 1, __ATOMIC_RELAXED, __HIP_MEMORY_SCOPE_AGENT);
    if ((o2 & 15) == 15)
      __hip_atomic_fetch_add(gen, 1, __ATOMIC_RELAXED, __HIP_MEMORY_SCOPE_AGENT);
  }
  while (__hip_atomic_load(gen, __ATOMIC_RELAXED, __HIP_MEMORY_SCOPE_AGENT) < target)
    __builtin_amdgcn_s_sleep(1);
}

// ============ packed {phase, delta} flag barrier — contiguous 8B slots ============
__device__ __forceinline__ void pbar_wave0(
    unsigned long long* pslot, int ph, int* sdm, float* sdelta_sh, int lane)
{
  const int par = ph & 1;
  unsigned long long* base = pslot + (size_t)par * NBLK;
  if (lane == 0){
    int myd = sdm[par]; sdm[par] = 0;
    unsigned long long pack =
        ((unsigned long long)(unsigned int)myd << 32) | (unsigned int)ph;
    __builtin_amdgcn_s_waitcnt(0);          // all prior y stores drained
    astore64(&base[blockIdx.x], pack);
  }
  int mx;
  while (1){
    unsigned long long v0 = aload64(&base[lane      ]);
    unsigned long long v1 = aload64(&base[lane +  64]);
    unsigned long long v2 = aload64(&base[lane + 128]);
    unsigned long long v3 = aload64(&base[lane + 192]);
    int f0 = (int)(unsigned int)v0, f1 = (int)(unsigned int)v1;
    int f2 = (int)(unsigned int)v2, f3 = (int)(unsigned int)v3;
    int mn = f0 < f1 ? f0 : f1;
    mn = f2 < mn ? f2 : mn;
    mn = f3 < mn ? f3 : mn;
    if (__all(mn >= ph)){
      int d0 = (int)(v0 >> 32), d1 = (int)(v1 >> 32);
      int d2 = (int)(v2 >> 32), d3 = (int)(v3 >> 32);
      mx = d0 > d1 ? d0 : d1;
      mx = d2 > mx ? d2 : mx;
      mx = d3 > mx ? d3 : mx;
      break;
    }
    __builtin_amdgcn_s_sleep(1);
  }
  #pragma unroll
  for (int o = 32; o; o >>= 1){ int ox = __shfl_xor(mx, o, 64); mx = ox > mx ? ox : mx; }
  if (lane == 0) *sdelta_sh = __int_as_float(mx);
}

// ---- R17: chunked SpMV. K groups (K<=4) of 8 edges: ALL 8K y-loads issue
//      concurrently (one LLC round-trip instead of K serialized), then the
//      fma sequence runs in the EXACT old order (groups ascending, edge u ->
//      accumulator u) -> bit-identical. Arrays are fully unrolled with
//      compile-time indices -> registers (no scratch).
template<int K>
__device__ __forceinline__ void chunk_fma(
    const float* __restrict__ src, const int2* adj, int gbase, int lane,
    float& s0, float& s1, float& s2, float& s3,
    float& s4, float& s5, float& s6, float& s7)
{
  float yv[K][8], wv[K][8];
  #pragma unroll
  for (int g = 0; g < K; g++){
    #pragma unroll
    for (int u = 0; u < 8; u++){
      int2 a = adj[(gbase + g) * 8 + u];
      wv[g][u] = __int_as_float(a.y);
      yv[g][u] = aload(&src[a.x + lane]);
    }
  }
  #pragma unroll
  for (int g = 0; g < K; g++){
    s0 = fmaf(wv[g][0], yv[g][0], s0);
    s1 = fmaf(wv[g][1], yv[g][1], s1);
    s2 = fmaf(wv[g][2], yv[g][2], s2);
    s3 = fmaf(wv[g][3], yv[g][3], s3);
    s4 = fmaf(wv[g][4], yv[g][4], s4);
    s5 = fmaf(wv[g][5], yv[g][5], s5);
    s6 = fmaf(wv[g][6], yv[g][6], s6);
    s7 = fmaf(wv[g][7], yv[g][7], s7);
  }
}

// ---- SpMV over one row. R17: all-upfront loads per <=4-group chunk; agent
//      loads restored (R16's plain-load + fence combo measured -8us). The
//      remainder (deg%8) is also pre-loaded concurrently then chained into
//      s0 in ascending order. FP order identical to R13/R14/R15.
__device__ __forceinline__ float spmv_row(
    const float* __restrict__ src, const int2* adj,
    const int* __restrict__ colA, const float* __restrict__ wA,
    int p0, int p1v, int lane)
{
  const int deg  = p1v - p0;
  const int ncap = deg < ADJ_CAP ? deg : ADJ_CAP;
  const int nfull = ncap & ~7;
  const int ng = nfull >> 3;
  float s0=0.f,s1=0.f,s2=0.f,s3=0.f,s4=0.f,s5=0.f,s6=0.f,s7=0.f;

  int g = 0;
  #pragma unroll 1
  for (; g + 4 <= ng; g += 4){
    chunk_fma<4>(src, adj, g, lane, s0,s1,s2,s3,s4,s5,s6,s7);
  }
  {
    const int left = ng - g;
    if (left == 3)      chunk_fma<3>(src, adj, g, lane, s0,s1,s2,s3,s4,s5,s6,s7);
    else if (left == 2) chunk_fma<2>(src, adj, g, lane, s0,s1,s2,s3,s4,s5,s6,s7);
    else if (left == 1) chunk_fma<1>(src, adj, g, lane, s0,s1,s2,s3,s4,s5,s6,s7);
  }

  if (deg > ADJ_CAP){
    // overflow beyond LDS capacity (rare): identical old serial mapping.
    int qg = p0 + ADJ_CAP;
    for (; qg + 8 <= p1v; qg += 8){
      s0 = fmaf(wA[qg    ], aload(&src[colA[qg    ] + lane]), s0);
      s1 = fmaf(wA[qg + 1], aload(&src[colA[qg + 1] + lane]), s1);
      s2 = fmaf(wA[qg + 2], aload(&src[colA[qg + 2] + lane]), s2);
      s3 = fmaf(wA[qg + 3], aload(&src[colA[qg + 3] + lane]), s3);
      s4 = fmaf(wA[qg + 4], aload(&src[colA[qg + 4] + lane]), s4);
      s5 = fmaf(wA[qg + 5], aload(&src[colA[qg + 5] + lane]), s5);
      s6 = fmaf(wA[qg + 6], aload(&src[colA[qg + 6] + lane]), s6);
      s7 = fmaf(wA[qg + 7], aload(&src[colA[qg + 7] + lane]), s7);
    }
    for (; qg < p1v; qg++)
      s0 = fmaf(wA[qg], aload(&src[colA[qg] + lane]), s0);
  } else {
    // remainder from LDS adj: concurrent predicated loads, then ascending
    // fma chain into s0 (same order as the old serial loop).
    const int rem = deg - nfull;            // 0..7
    if (rem > 0){
      float yr[7], wr[7];
      #pragma unroll
      for (int u = 0; u < 7; u++){
        if (u < rem){
          int2 a = adj[nfull + u];
          wr[u] = __int_as_float(a.y);
          yr[u] = aload(&src[a.x + lane]);
        }
      }
      #pragma unroll
      for (int u = 0; u < 7; u++)
        if (u < rem) s0 = fmaf(wr[u], yr[u], s0);
    }
  }
  return ((s0+s1)+(s2+s3)) + ((s4+s5)+(s6+s7));
}

// ---- fused tail. R17: chunked-MLP SpMV (one LLC round per <=32-edge row),
//      agent-scope y-gather restored, no per-iteration fences (R15 pbar
//      semantics: publish drains stores; poll carries deltas).
__global__ __launch_bounds__(1024, 4) void tail_loop(
    const float* __restrict__ Xq, const float* __restrict__ Pt,
    const float* __restrict__ pn, const float* __restrict__ qn,
    const int* __restrict__ nbr, const float* __restrict__ dnbr,
    const float* __restrict__ sigma,
    float* d2min, float* denom, float* wh,
    float* rowsum, int* indeg, int* rowptr, int* fillc,
    int* colA, float* wA, float* buf0, float* buf1,
    unsigned long long* pslot,
    int* gcnt, int* gen, int* garr, int* __restrict__ out)
{
  __shared__ int   sdm[2];
  __shared__ float sdelta;
  __shared__ union {
    float pchunk[CHK * N_C];                // 64 KB, P0a staging
    struct {
      int   ipart[1024];
      int   hist[1024];
      float cand[4096];
      int   candn, b1s, b2s;
    } s;
  } U;
  __shared__ int2  adjL[16 * ADJ_CAP];      // 12 KB, per-wave adjacency

  const int tid  = threadIdx.x;
  const int lane = tid & 63;
  const int wv   = tid >> 6;
  const int row  = blockIdx.x * 16 + wv;
  if (tid == 0){ sdm[0] = 0; sdm[1] = 0; }

  // ---------- P0a: a-row via LDS-staged Pt chunks (bit-exact dp order) ----------
  const float* xr = Xq + (size_t)row * DIM;
  const f4*    xr4 = (const f4*)xr;
  float dp[8];
  #pragma unroll
  for (int u = 0; u < 8; u++) dp[u] = 0.f;

  for (int f0 = 0; f0 < DIM; f0 += CHK){
    // cooperative stage: CHK*64 floats = 4096 f4; 1024 threads x 4 f4
    const f4* srcv = (const f4*)(Pt + (size_t)f0 * N_C);
    f4* dstv = (f4*)U.pchunk;
    #pragma unroll
    for (int u = 0; u < 4; u++) dstv[tid + u * 1024] = srcv[tid + u * 1024];
    __syncthreads();
    #pragma unroll 1
    for (int f = 0; f < CHK; f += 8){
      const f4 xa = xr4[(f0 + f) >> 2];
      const f4 xb = xr4[((f0 + f) >> 2) + 1];
      const float* pc = U.pchunk + f * N_C + lane;
      dp[0] = fmaf(xa[0], pc[0      ], dp[0]);
      dp[1] = fmaf(xa[1], pc[N_C    ], dp[1]);
      dp[2] = fmaf(xa[2], pc[N_C * 2], dp[2]);
      dp[3] = fmaf(xa[3], pc[N_C * 3], dp[3]);
      dp[4] = fmaf(xb[0], pc[N_C * 4], dp[4]);
      dp[5] = fmaf(xb[1], pc[N_C * 5], dp[5]);
      dp[6] = fmaf(xb[2], pc[N_C * 6], dp[6]);
      dp[7] = fmaf(xb[3], pc[N_C * 7], dp[7]);
    }
    __syncthreads();                        // before next chunk overwrite
  }
  const float dot = ((dp[0]+dp[1])+(dp[2]+dp[3])) + ((dp[4]+dp[5])+(dp[6]+dp[7]));
  const float av  = fmaxf(qn[row] + pn[lane] - 2.0f * dot, 0.0f);
  const float d2m = wave_min64(av);
  if (lane == 0) astore(&d2min[row], d2m);

  // ---------- P0b: edge weights + degrees ----------
  const int e = blockIdx.x * 1024 + tid;
  if (e < N_Q * KNN){
    const int i = e / KNN;
    const int j = nbr[e];
    float wgt = 0.5f * expf(-dnbr[e] / (sigma[i] * sigma[j]));
    astore(&wh[e], wgt);
    atomicAdd(&rowsum[i], wgt);
    atomicAdd(&rowsum[j], wgt);
    atomicAdd(&indeg[j], 1);
  }

  __syncthreads();
  if (tid == 0) gbar_leader(garr, gcnt, gen, 1);
  __syncthreads();

  // ---------- P1: y0 + scan (block 0) + median (block 1) ----------
  float xv = -av;
  float m = wave_max64(xv), ee = expf(xv - m), ss = wave_sum64(ee);
  float prev = ee / ss;                    // y0
  astore(&buf0[row * N_C + lane], prev);

  if (blockIdx.x == 0){
    int* ipart = U.s.ipart;
    const int base = tid * 4;
    int c0 = aloadi(&indeg[base]),     c1 = aloadi(&indeg[base + 1]);
    int c2 = aloadi(&indeg[base + 2]), c3 = aloadi(&indeg[base + 3]);
    const int s4 = c0 + c1 + c2 + c3;
    ipart[tid] = s4;
    __syncthreads();
    for (int off = 1; off < 1024; off <<= 1){
      int v = (tid >= off) ? ipart[tid - off] : 0;
      __syncthreads();
      ipart[tid] += v;
      __syncthreads();
    }
    int run = ipart[tid] - s4;
    astorei(&rowptr[base    ], KNN * (base    ) + run); run += c0;
    astorei(&rowptr[base + 1], KNN * (base + 1) + run); run += c1;
    astorei(&rowptr[base + 2], KNN * (base + 2) + run); run += c2;
    astorei(&rowptr[base + 3], KNN * (base + 3) + run);
    if (tid == 1023) astorei(&rowptr[N_Q], KNN * N_Q + ipart[1023]);
  }
  if (blockIdx.x == 1){
    int*   hist = U.s.hist;
    float* cand = U.s.cand;
    const int base = tid * 4;
    float dv[4];
    #pragma unroll
    for (int u = 0; u < 4; u++) dv[u] = sqrtf(aload(&d2min[base + u]));
    float mn = fminf(fminf(dv[0], dv[1]), fminf(dv[2], dv[3]));
    float mx = fmaxf(fmaxf(dv[0], dv[1]), fmaxf(dv[2], dv[3]));
    mn = wave_min64(mn); mx = wave_max64(mx);
    if (lane == 0){ cand[wv] = mn; cand[wv + 16] = mx; }
    __syncthreads();
    if (tid == 0){
      float a = cand[0], b = cand[16];
      for (int k = 1; k < 16; k++){ a = fminf(a, cand[k]); b = fmaxf(b, cand[16 + k]); }
      cand[32] = a; cand[33] = b;
    }
    __syncthreads();
    mn = cand[32]; mx = cand[33];
    const float rng = mx - mn;
    const float scale = (rng > 0.f) ? (1024.0f / rng) : 0.f;
    hist[tid] = 0;
    __syncthreads();
    int bidx[4];
    #pragma unroll
    for (int u = 0; u < 4; u++){
      int b = (int)((dv[u] - mn) * scale);
      b = b < 0 ? 0 : (b > 1023 ? 1023 : b);
      bidx[u] = b;
      atomicAdd(&hist[b], 1);
    }
    __syncthreads();
    for (int off = 1; off < 1024; off <<= 1){
      int v = (tid >= off) ? hist[tid - off] : 0;
      __syncthreads();
      hist[tid] += v;
      __syncthreads();
    }
    if (hist[tid] >= 2048 && (tid == 0 || hist[tid - 1] < 2048)) U.s.b1s = tid;
    if (hist[tid] >= 2049 && (tid == 0 || hist[tid - 1] < 2049)) U.s.b2s = tid;
    if (tid == 0) U.s.candn = 0;
    __syncthreads();
    const int b1 = U.s.b1s, b2 = U.s.b2s;
    const int cntBefore = (b1 > 0) ? hist[b1 - 1] : 0;
    #pragma unroll
    for (int u = 0; u < 4; u++){
      if (bidx[u] >= b1 && bidx[u] <= b2){
        int pos = atomicAdd(&U.s.candn, 1);
        cand[pos] = dv[u];
      }
    }
    __syncthreads();
    const int mcnt = U.s.candn;
    int P = 2; while (P < mcnt) P <<= 1;
    for (int i2 = mcnt + tid; i2 < P; i2 += 1024) cand[i2] = FLT_MAX;
    __syncthreads();
    for (int k = 2; k <= P; k <<= 1){
      for (int st = k >> 1; st > 0; st >>= 1){
        for (int i2 = tid; i2 < P; i2 += 1024){
          int j2 = i2 ^ st;
          if (j2 > i2){
            float a2 = cand[i2], b3 = cand[j2];
            bool up = ((i2 & k) == 0);
            if (up ? (a2 > b3) : (a2 < b3)){ cand[i2] = b3; cand[j2] = a2; }
          }
        }
        __syncthreads();
      }
    }
    if (tid == 0){
      float v1 = cand[2047 - cntBefore], v2 = cand[2048 - cntBefore];
      float med = 0.5f * (v1 + v2);
      astore(denom, 2.0f * med * med + 1e-8f);
    }
  }

  __syncthreads();
  if (tid == 0) gbar_leader(garr, gcnt, gen, 2);
  __syncthreads();

  // ---------- P2: CSR fill + per-row coef ----------
  if (e < N_Q * KNN){
    const int i = e / KNN, tt = e % KNN;
    const int j = nbr[e];
    const float wgt = aload(&wh[e]);
    const int p = aloadi(&rowptr[i]) + tt;
    colA[p] = j * N_C; wA[p] = wgt;
    const int q = aloadi(&rowptr[j]) + KNN + atomicAdd(&fillc[j], 1);
    colA[q] = i * N_C; wA[q] = wgt;
  }
  const float cf = expf(-d2m / aload(denom)) / (aload(&rowsum[row]) + 1e-8f);
  const int p0  = aloadi(&rowptr[row]);
  const int p1v = aloadi(&rowptr[row + 1]);

  __builtin_amdgcn_fence(__ATOMIC_RELEASE, "agent");
  __syncthreads();
  if (tid == 0) gbar_leader(garr, gcnt, gen, 3);
  __syncthreads();
  __builtin_amdgcn_fence(__ATOMIC_ACQUIRE, "agent");

  // ---------- preload loop-invariant adjacency into LDS ----------
  {
    const int deg  = p1v - p0;
    const int ncap = deg < ADJ_CAP ? deg : ADJ_CAP;
    for (int u = lane; u < ncap; u += 64)
      adjL[wv * ADJ_CAP + u] = make_int2(colA[p0 + u], __float_as_int(wA[p0 + u]));
  }
  __syncthreads();
  const int2* adj = adjL + wv * ADJ_CAP;

  // ---------- P3: y1 = step(y0); publish delta via pbar phase 1 ----------
  float cur;
  {
    float sum = spmv_row(buf0, adj, colA, wA, p0, p1v, lane);
    float xv2 = -av + cf * sum;
    float mm = wave_max64(xv2), e2 = expf(xv2 - mm), ss2 = wave_sum64(e2);
    cur = e2 / ss2;
    astore(&buf1[row * N_C + lane], cur);
  }
  float dm = wave_max64(fabsf(cur - prev));
  if (lane == 0) atomicMax(&sdm[1], __float_as_int(dm));
  __syncthreads();                         // drains all waves' y stores + LDS
  if (wv == 0) pbar_wave0(pslot, 1, sdm, &sdelta, lane);
  __syncthreads();
  float delta = sdelta;

  // ---------- P4: the while-loop ----------
  int par = 1;                             // buffer currently holding y_new
  for (int t = 0;; t++){
    if (t >= MAX_ITER || delta < EPS_CONV) break;
    const float* src = par ? buf1 : buf0;
    float*       dst = par ? buf0 : buf1;
    float sum = spmv_row(src, adj, colA, wA, p0, p1v, lane);
    float xv2 = -av + cf * sum;
    float mm = wave_max64(xv2), e2 = expf(xv2 - mm), ss2 = wave_sum64(e2);
    float nxt = e2 / ss2;
    astore(&dst[row * N_C + lane], nxt);
    const int ph = t + 2;
    dm = wave_max64(fabsf(nxt - cur));
    if (lane == 0) atomicMax(&sdm[ph & 1], __float_as_int(dm));
    __syncthreads();
    if (wv == 0) pbar_wave0(pslot, ph, sdm, &sdelta, lane);
    __syncthreads();
    delta = sdelta;
    prev = cur; cur = nxt; par ^= 1;
  }

  // argmax of y (prev); first occurrence on ties
  float bv = prev; int bi = lane;
  #pragma unroll
  for (int o = 32; o; o >>= 1){
    float ov = __shfl_xor(bv, o, 64); int oi = __shfl_xor(bi, o, 64);
    if (ov > bv || (ov == bv && oi < bi)){ bv = ov; bi = oi; }
  }
  if (lane == 0) out[row] = bi;
}

extern "C" void kernel_launch(void* const* d_in, const int* in_sizes, int n_in,
                              void* d_out, int out_size, void* d_ws, size_t ws_size,
                              hipStream_t stream)
{
  const float* feat_s = (const float*)d_in[0];
  const int*   y_s    = (const int*)d_in[1];
  const float* feat_q = (const float*)d_in[2];
  int* out = (int*)d_out;

  char* wp = (char*)d_ws;
  auto alloc = [&](size_t bytes) -> char* {
    char* p = wp;
    wp += (bytes + 255) & ~(size_t)255;
    return p;
  };
  float*     Dq  = (float*)alloc((size_t)N_Q * N_Q * 4);     // 64 MB
  _Float16*  Xh  = (_Float16*)alloc((size_t)N_Q * DIM * 2);  // 8 MB
  _Float16*  Xl  = (_Float16*)alloc((size_t)N_Q * DIM * 2);  // 8 MB
  float* Pt     = (float*)alloc((size_t)DIM * N_C * 4);
  float* pn     = (float*)alloc(N_C * 4);
  float* qn     = (float*)alloc(N_Q * 4);
  float* d2min  = (float*)alloc(N_Q * 4);
  float* denom  = (float*)alloc(256);
  int*   nbr    = (int*)alloc((size_t)N_Q * KNN * 4);
  float* dnbr   = (float*)alloc((size_t)N_Q * KNN * 4);
  float* sigma  = (float*)alloc(N_Q * 4);
  float* wh     = (float*)alloc((size_t)N_Q * KNN * 4);
  int*   rowptr = (int*)alloc((N_Q + 1) * 4);
  int*   colA   = (int*)alloc((size_t)2 * N_Q * KNN * 4);
  float* wA     = (float*)alloc((size_t)2 * N_Q * KNN * 4);
  float* buf0   = (float*)alloc((size_t)N_Q * N_C * 4);
  float* buf1   = (float*)alloc((size_t)N_Q * N_C * 4);
  // zero-region: rowsum | indeg | fillc | syncw | garr | pslot (packed, 4KB)
  const size_t zbytes = (size_t)N_Q*12 + 256 + 2048 + 2 * NBLK * 8;
  char*  zbase  = alloc(zbytes);
  float* rowsum = (float*)(zbase);
  int*   indeg  = (int*)(zbase + N_Q*4);
  int*   fillc  = (int*)(zbase + N_Q*8);
  int*   syncw  = (int*)(zbase + N_Q*12);
  int*   garr   = (int*)(zbase + N_Q*12 + 256);
  unsigned long long* pslot = (unsigned long long*)(zbase + N_Q*12 + 256 + 2048);

  hipMemsetAsync(zbase, 0, zbytes, stream);

  proto_kernel <<<N_C, 256, 0, stream>>>(feat_s, y_s, Pt, pn);
  prep_kernel  <<<N_Q, 256, 0, stream>>>(feat_q, qn, Xh, Xl);
  dist_mfma    <<<dim3(N_Q/128, N_Q/128), 256, 0, stream>>>(Xh, Xl, qn, Dq);
  topk_kernel  <<<N_Q, 256, 0, stream>>>(Dq, nbr, dnbr, sigma);

  int* gcnt = &syncw[0];
  int* gen  = &syncw[32];
  const float* Xq = feat_q;
  void* args[] = {&Xq, &Pt, &pn, &qn, &nbr, &dnbr, &sigma,
                  &d2min, &denom, &wh, &rowsum, &indeg, &rowptr, &fillc,
                  &colA, &wA, &buf0, &buf1, &pslot,
                  &gcnt, &gen, &garr, &out};
  hipLaunchCooperativeKernel((void*)tail_loop, dim3(NBLK), dim3(1024), args, 0, stream);
}